// Round 2
// baseline (396.316 us; speedup 1.0000x reference)
//
#include <hip/hip_runtime.h>
#include <hip/hip_bf16.h>

#define HW 16384
#define NMOD 4
#define CPM 64
#define NPM (CPM*HW)   // 1048576 elements per (b, modality)
#define NC 256
#define NO 64
#define EPS_IN 1e-5f

typedef float f32x4 __attribute__((ext_vector_type(4)));
typedef short bhalf8 __attribute__((ext_vector_type(8)));

static __device__ __forceinline__ short f2bf(float f){
  __bf16 h = (__bf16)f;              // v_cvt to bf16 (RNE); compiler pairs into cvt_pk
  return __builtin_bit_cast(short, h);
}

// ws layout (floats): [0,256) dots[b][i*4+j] (i<=j), [256,320) probs[b][m], [320,2368) stats[(b*64+o)*2 + {sum,sumsq}]
__global__ void k_zero(float* ws){
  int i = blockIdx.x*256 + threadIdx.x;
  if (i < 2368) ws[i] = 0.f;
}

__global__ void k_dots(const float* __restrict__ x, float* __restrict__ dots){
  int b = blockIdx.y;
  const float4* xb = reinterpret_cast<const float4*>(x) + (size_t)b*(NMOD*(size_t)NPM/4);
  float acc[4][4];
  #pragma unroll
  for (int i=0;i<4;i++)
    #pragma unroll
    for (int j=0;j<4;j++) acc[i][j]=0.f;
  int stride = gridDim.x * blockDim.x;
  for (int p = blockIdx.x*blockDim.x + threadIdx.x; p < NPM/4; p += stride){
    float4 v[4];
    #pragma unroll
    for (int m=0;m<4;m++) v[m] = xb[p + m*(NPM/4)];
    #pragma unroll
    for (int i=0;i<4;i++)
      #pragma unroll
      for (int j=i;j<4;j++)
        acc[i][j] += v[i].x*v[j].x + v[i].y*v[j].y + v[i].z*v[j].z + v[i].w*v[j].w;
  }
  #pragma unroll
  for (int i=0;i<4;i++)
    #pragma unroll
    for (int j=i;j<4;j++){
      float s = acc[i][j];
      #pragma unroll
      for (int off=32; off; off>>=1) s += __shfl_down(s, off, 64);
      if ((threadIdx.x & 63) == 0) atomicAdd(&dots[b*16 + i*4 + j], s);
    }
}

__global__ void k_attn(float* ws){
  int b = threadIdx.x;
  if (b < 16){
    const float* d = ws + b*16;
    float nrm[4];
    #pragma unroll
    for (int m=0;m<4;m++) nrm[m] = fmaxf(sqrtf(d[m*4+m]), 1e-8f);
    float sc[4];
    #pragma unroll
    for (int i=0;i<4;i++){
      float s = 0.f;
      #pragma unroll
      for (int j=0;j<4;j++){
        float dij = (i<=j) ? d[i*4+j] : d[j*4+i];
        s += dij / (nrm[i]*nrm[j]);
      }
      sc[i] = -(s - 1.0f);  // subtract the diagonal of eye
    }
    float mx = fmaxf(fmaxf(sc[0],sc[1]), fmaxf(sc[2],sc[3]));
    float e[4], se = 0.f;
    #pragma unroll
    for (int m=0;m<4;m++){ e[m] = expf(sc[m]-mx); se += e[m]; }
    #pragma unroll
    for (int m=0;m<4;m++) ws[256 + b*4 + m] = e[m]/se;
  }
}

// GEMM: Y[b] = (W * prob[b]) @ X[b].  A (weights) register-resident, B gathered from global.
// Block: 4 waves, 512 pixels; each wave owns all 64 output rows x 16-pixel col-tiles.
__launch_bounds__(256, 2)
__global__ void k_gemm(const float* __restrict__ x, const float* __restrict__ w,
                       const float* __restrict__ ws, float* __restrict__ y,
                       float* __restrict__ stats){
  const int b   = blockIdx.y;
  const int wid = threadIdx.x >> 6;
  const int lane = threadIdx.x & 63;
  const int l15 = lane & 15;
  const int lg  = lane >> 4;

  const float* probs = ws + 256 + b*4;
  float pm[4] = {probs[0], probs[1], probs[2], probs[3]};

  // A fragments: row = rt*16 + (lane&15); k-mapping (lg,e) -> c = ks*32 + 4*lg + (e&3) + 16*(e>>2)
  // (k bijection is consistent with the B fragment below -> exact regardless of HW's internal k order)
  bhalf8 afrag[4][8];
  const float4* w4 = reinterpret_cast<const float4*>(w);
  #pragma unroll
  for (int rt=0; rt<4; rt++){
    int row = rt*16 + l15;
    #pragma unroll
    for (int ks=0; ks<8; ks++){
      float s = pm[ks>>1];                 // modality = (ks*32)>>6, constant within this 32-k block
      float4 a0 = w4[row*64 + ks*8 + lg];
      float4 a1 = w4[row*64 + ks*8 + lg + 4];
      bhalf8 f;
      f[0]=f2bf(a0.x*s); f[1]=f2bf(a0.y*s); f[2]=f2bf(a0.z*s); f[3]=f2bf(a0.w*s);
      f[4]=f2bf(a1.x*s); f[5]=f2bf(a1.y*s); f[6]=f2bf(a1.z*s); f[7]=f2bf(a1.w*s);
      afrag[rt][ks] = f;
    }
  }

  const float* xb = x + (size_t)b*NC*HW;
  float sacc[4][4] = {{0}}, qacc[4][4] = {{0}};
  const int base = blockIdx.x * 512;

  #pragma unroll 1
  for (int it=0; it<8; it++){
    int n0 = base + wid*16 + it*64;
    f32x4 acc[4];
    #pragma unroll
    for (int rt=0; rt<4; rt++) acc[rt] = (f32x4){0.f,0.f,0.f,0.f};

    #pragma unroll
    for (int ks=0; ks<8; ks++){
      bhalf8 bfr;
      #pragma unroll
      for (int eh=0; eh<2; eh++)
        #pragma unroll
        for (int el=0; el<4; el++){
          int c = ks*32 + lg*4 + el + eh*16;
          bfr[eh*4+el] = f2bf(xb[(size_t)c*HW + n0 + l15]);
        }
      #pragma unroll
      for (int rt=0; rt<4; rt++)
        acc[rt] = __builtin_amdgcn_mfma_f32_16x16x32_bf16(afrag[rt][ks], bfr, acc[rt], 0, 0, 0);
    }

    // C/D layout (verified): row = (lane>>4)*4 + reg, col = lane&15
    size_t ybase = ((size_t)b*NO)*HW + n0 + l15;
    #pragma unroll
    for (int rt=0; rt<4; rt++){
      #pragma unroll
      for (int r=0; r<4; r++){
        int o = rt*16 + lg*4 + r;
        float v = acc[rt][r];
        y[ybase + (size_t)o*HW] = v;
        sacc[rt][r] += v;
        qacc[rt][r] += v*v;
      }
    }
  }

  // stats: reduce the 16 pixels (lanes with same lg) then atomics
  #pragma unroll
  for (int rt=0; rt<4; rt++){
    #pragma unroll
    for (int r=0; r<4; r++){
      float s = sacc[rt][r], q = qacc[rt][r];
      #pragma unroll
      for (int off=1; off<16; off<<=1){
        s += __shfl_xor(s, off, 64);
        q += __shfl_xor(q, off, 64);
      }
      if (l15 == 0){
        int o = rt*16 + lg*4 + r;
        atomicAdd(&stats[(b*NO + o)*2],     s);
        atomicAdd(&stats[(b*NO + o)*2 + 1], q);
      }
    }
  }
}

__global__ void k_norm(float* __restrict__ y, const float* __restrict__ stats){
  int bo = blockIdx.x;            // b*64 + o
  float s = stats[bo*2], q = stats[bo*2+1];
  float mean = s * (1.f/HW);
  float var  = q * (1.f/HW) - mean*mean;
  float inv  = rsqrtf(var + EPS_IN);
  float4* yp = reinterpret_cast<float4*>(y) + (size_t)bo*(HW/4);
  #pragma unroll 4
  for (int i = threadIdx.x; i < HW/4; i += 256){
    float4 v = yp[i];
    v.x = fmaxf((v.x-mean)*inv, 0.f);
    v.y = fmaxf((v.y-mean)*inv, 0.f);
    v.z = fmaxf((v.z-mean)*inv, 0.f);
    v.w = fmaxf((v.w-mean)*inv, 0.f);
    yp[i] = v;
  }
}

extern "C" void kernel_launch(void* const* d_in, const int* in_sizes, int n_in,
                              void* d_out, int out_size, void* d_ws, size_t ws_size,
                              hipStream_t stream){
  const float* x = (const float*)d_in[0];
  const float* w = (const float*)d_in[1];
  float* out = (float*)d_out;
  float* ws  = (float*)d_ws;
  float* stats = ws + 320;

  k_zero<<<dim3(10), dim3(256), 0, stream>>>(ws);
  k_dots<<<dim3(128,16), dim3(256), 0, stream>>>(x, ws);
  k_attn<<<dim3(1), dim3(64), 0, stream>>>(ws);
  k_gemm<<<dim3(32,16), dim3(256), 0, stream>>>(x, w, ws, out, stats);
  k_norm<<<dim3(1024), dim3(256), 0, stream>>>(out, stats);
}

// Round 3
// 243.352 us; speedup vs baseline: 1.6286x; 1.6286x over previous
//
#include <hip/hip_runtime.h>
#include <hip/hip_bf16.h>

#define HW 16384
#define NC 256
#define NO 64
#define NPM 1048576          // floats per (b, modality)
#define EPS_IN 1e-5f
#define NBLK 128             // blocks.x for k_dots
#define WIN 1024             // floats per modality per window
#define NIT 8                // NPM / (NBLK*WIN)

typedef float f32x4 __attribute__((ext_vector_type(4)));
typedef short bhalf8 __attribute__((ext_vector_type(8)));

static __device__ __forceinline__ short f2bf(float f){
  __bf16 h = (__bf16)f;
  return __builtin_bit_cast(short, h);
}

// ws float layout: [256,320) probs[b][m] ; [320,2368) stats[(b*64+o)*2+{s,q}] ;
//                  [4096, 4096+16*NBLK*10) block partials (no atomics)

__global__ void k_zero(float* ws){
  int i = blockIdx.x*256 + threadIdx.x;
  if (i < 2048) ws[320 + i] = 0.f;   // stats only
}

// Pass 1: Gram-matrix partials. Each wave streams ONE contiguous modality into
// LDS (global_load_lds, linear dest); block computes 10 pair-dots from LDS.
__global__ void k_dots(const float* __restrict__ x, float* __restrict__ partials){
  __shared__ float lds[4][WIN];
  const int b = blockIdx.y, bx = blockIdx.x;
  const int tid = threadIdx.x;
  const int w = tid >> 6, lane = tid & 63;
  const float* xw = x + (size_t)b*4*NPM + (size_t)w*NPM;  // this wave's modality

  float acc[10];
  #pragma unroll
  for (int k=0;k<10;k++) acc[k]=0.f;

  for (int it=0; it<NIT; it++){
    int n0 = (it*NBLK + bx)*WIN;
    #pragma unroll
    for (int li=0; li<4; li++){
      const float* src = xw + n0 + li*256 + lane*4;       // 16B/lane, contiguous 1KB/wave-load
      __builtin_amdgcn_global_load_lds(
          (const __attribute__((address_space(1))) void*)src,
          (__attribute__((address_space(3))) void*)&lds[w][li*256],
          16, 0, 0);
    }
    __syncthreads();                                      // drains vmcnt -> LDS ready
    float4 vv[4];
    #pragma unroll
    for (int m=0;m<4;m++) vv[m] = *(const float4*)&lds[m][tid*4];
    int k=0;
    #pragma unroll
    for (int i=0;i<4;i++)
      #pragma unroll
      for (int j=i;j<4;j++,k++)
        acc[k] += vv[i].x*vv[j].x + vv[i].y*vv[j].y + vv[i].z*vv[j].z + vv[i].w*vv[j].w;
    __syncthreads();                                      // all reads done before next overwrite
  }

  // wave reduce -> cross-wave via LDS -> one plain store per block (no atomics)
  #pragma unroll
  for (int k=0;k<10;k++){
    float s = acc[k];
    #pragma unroll
    for (int off=1; off<64; off<<=1) s += __shfl_xor(s, off, 64);
    acc[k]=s;
  }
  __syncthreads();
  if (lane==0){
    #pragma unroll
    for (int k=0;k<10;k++) lds[0][w*16+k] = acc[k];
  }
  __syncthreads();
  if (tid<10){
    float s = lds[0][tid] + lds[0][16+tid] + lds[0][32+tid] + lds[0][48+tid];
    partials[((size_t)b*NBLK + bx)*10 + tid] = s;
  }
}

// Pass 2: reduce 128 partials per batch, cosine scores, softmax -> probs
__global__ void k_attn(const float* __restrict__ partials, float* __restrict__ probs){
  __shared__ float red[2][16];
  int b = blockIdx.x, tid = threadIdx.x;       // 128 threads
  int w = tid>>6, lane = tid&63;
  float a[10];
  const float* p = partials + ((size_t)b*NBLK + tid)*10;
  #pragma unroll
  for (int k=0;k<10;k++) a[k]=p[k];
  #pragma unroll
  for (int k=0;k<10;k++){
    float s=a[k];
    #pragma unroll
    for (int off=1;off<64;off<<=1) s+=__shfl_xor(s,off,64);
    a[k]=s;
  }
  if (lane==0){
    #pragma unroll
    for (int k=0;k<10;k++) red[w][k]=a[k];
  }
  __syncthreads();
  if (tid==0){
    float d[10];
    #pragma unroll
    for (int k=0;k<10;k++) d[k]=red[0][k]+red[1][k];
    float D[4][4];
    int k=0;
    #pragma unroll
    for (int i=0;i<4;i++)
      #pragma unroll
      for (int j=i;j<4;j++,k++){ D[i][j]=d[k]; D[j][i]=d[k]; }
    float nrm[4];
    #pragma unroll
    for (int m=0;m<4;m++) nrm[m]=fmaxf(sqrtf(D[m][m]),1e-8f);
    float sc[4];
    #pragma unroll
    for (int i=0;i<4;i++){
      float s=0.f;
      #pragma unroll
      for (int j=0;j<4;j++) s += D[i][j]/(nrm[i]*nrm[j]);
      sc[i] = -(s-1.0f);
    }
    float mx = fmaxf(fmaxf(sc[0],sc[1]), fmaxf(sc[2],sc[3]));
    float e[4], se=0.f;
    #pragma unroll
    for (int m=0;m<4;m++){ e[m]=expf(sc[m]-mx); se+=e[m]; }
    #pragma unroll
    for (int m=0;m<4;m++) probs[b*4+m]=e[m]/se;
  }
}

// GEMM: Y[b] = (W * prob[b]) @ X[b].  A register-resident, B gathered from global.
__launch_bounds__(256, 2)
__global__ void k_gemm(const float* __restrict__ x, const float* __restrict__ w,
                       const float* __restrict__ ws, float* __restrict__ y,
                       float* __restrict__ stats){
  const int b   = blockIdx.y;
  const int wid = threadIdx.x >> 6;
  const int lane = threadIdx.x & 63;
  const int l15 = lane & 15;
  const int lg  = lane >> 4;

  const float* probs = ws + 256 + b*4;
  float pm[4] = {probs[0], probs[1], probs[2], probs[3]};

  bhalf8 afrag[4][8];
  const float4* w4 = reinterpret_cast<const float4*>(w);
  #pragma unroll
  for (int rt=0; rt<4; rt++){
    int row = rt*16 + l15;
    #pragma unroll
    for (int ks=0; ks<8; ks++){
      float s = pm[ks>>1];
      float4 a0 = w4[row*64 + ks*8 + lg];
      float4 a1 = w4[row*64 + ks*8 + lg + 4];
      bhalf8 f;
      f[0]=f2bf(a0.x*s); f[1]=f2bf(a0.y*s); f[2]=f2bf(a0.z*s); f[3]=f2bf(a0.w*s);
      f[4]=f2bf(a1.x*s); f[5]=f2bf(a1.y*s); f[6]=f2bf(a1.z*s); f[7]=f2bf(a1.w*s);
      afrag[rt][ks] = f;
    }
  }

  const float* xb = x + (size_t)b*NC*HW;
  float sacc[4][4] = {{0}}, qacc[4][4] = {{0}};
  const int base = blockIdx.x * 512;

  #pragma unroll 1
  for (int it=0; it<8; it++){
    int n0 = base + wid*16 + it*64;
    f32x4 acc[4];
    #pragma unroll
    for (int rt=0; rt<4; rt++) acc[rt] = (f32x4){0.f,0.f,0.f,0.f};

    #pragma unroll
    for (int ks=0; ks<8; ks++){
      bhalf8 bfr;
      #pragma unroll
      for (int eh=0; eh<2; eh++)
        #pragma unroll
        for (int el=0; el<4; el++){
          int c = ks*32 + lg*4 + el + eh*16;
          bfr[eh*4+el] = f2bf(xb[(size_t)c*HW + n0 + l15]);
        }
      #pragma unroll
      for (int rt=0; rt<4; rt++)
        acc[rt] = __builtin_amdgcn_mfma_f32_16x16x32_bf16(afrag[rt][ks], bfr, acc[rt], 0, 0, 0);
    }

    size_t ybase = ((size_t)b*NO)*HW + n0 + l15;
    #pragma unroll
    for (int rt=0; rt<4; rt++){
      #pragma unroll
      for (int r=0; r<4; r++){
        int o = rt*16 + lg*4 + r;
        float v = acc[rt][r];
        y[ybase + (size_t)o*HW] = v;
        sacc[rt][r] += v;
        qacc[rt][r] += v*v;
      }
    }
  }

  #pragma unroll
  for (int rt=0; rt<4; rt++){
    #pragma unroll
    for (int r=0; r<4; r++){
      float s = sacc[rt][r], q = qacc[rt][r];
      #pragma unroll
      for (int off=1; off<16; off<<=1){
        s += __shfl_xor(s, off, 64);
        q += __shfl_xor(q, off, 64);
      }
      if (l15 == 0){
        int o = rt*16 + lg*4 + r;
        atomicAdd(&stats[(b*NO + o)*2],     s);
        atomicAdd(&stats[(b*NO + o)*2 + 1], q);
      }
    }
  }
}

__global__ void k_norm(float* __restrict__ y, const float* __restrict__ stats){
  int bo = blockIdx.x;
  float s = stats[bo*2], q = stats[bo*2+1];
  float mean = s * (1.f/HW);
  float var  = q * (1.f/HW) - mean*mean;
  float inv  = rsqrtf(var + EPS_IN);
  float4* yp = reinterpret_cast<float4*>(y) + (size_t)bo*(HW/4);
  #pragma unroll 4
  for (int i = threadIdx.x; i < HW/4; i += 256){
    float4 v = yp[i];
    v.x = fmaxf((v.x-mean)*inv, 0.f);
    v.y = fmaxf((v.y-mean)*inv, 0.f);
    v.z = fmaxf((v.z-mean)*inv, 0.f);
    v.w = fmaxf((v.w-mean)*inv, 0.f);
    yp[i] = v;
  }
}

extern "C" void kernel_launch(void* const* d_in, const int* in_sizes, int n_in,
                              void* d_out, int out_size, void* d_ws, size_t ws_size,
                              hipStream_t stream){
  const float* x = (const float*)d_in[0];
  const float* w = (const float*)d_in[1];
  float* out = (float*)d_out;
  float* ws  = (float*)d_ws;
  float* partials = ws + 4096;
  float* probs    = ws + 256;
  float* stats    = ws + 320;

  k_zero<<<dim3(8),       dim3(256), 0, stream>>>(ws);
  k_dots<<<dim3(NBLK,16), dim3(256), 0, stream>>>(x, partials);
  k_attn<<<dim3(16),      dim3(128), 0, stream>>>(partials, probs);
  k_gemm<<<dim3(32,16),   dim3(256), 0, stream>>>(x, w, ws, out, stats);
  k_norm<<<dim3(1024),    dim3(256), 0, stream>>>(out, stats);
}